// Round 1
// baseline (353.052 us; speedup 1.0000x reference)
//
#include <hip/hip_runtime.h>

typedef __attribute__((ext_vector_type(4))) float  fx4;
typedef __attribute__((ext_vector_type(8))) short  s8;
typedef __attribute__((ext_vector_type(8))) unsigned short u8;

#define BD   8
#define CD   256
#define ND   16384
#define NH   8
#define DH   32
#define SCALE 0.17677669529663687f   // 1/sqrt(32)

#define GSPLIT 32
#define GKC (ND / GSPLIT)   // 512 fp32 cols per workgroup
#define GNT (GKC / 32)      // 16 K-steps of 32 fp32 cols

__device__ __forceinline__ unsigned short f2bf(float f) {
  unsigned int u = __float_as_uint(f);
  u += 0x7fffu + ((u >> 16) & 1u);      // RNE
  return (unsigned short)(u >> 16);
}
__device__ __forceinline__ float bf2f(unsigned short b) {
  return __uint_as_float(((unsigned int)b) << 16);
}

// convert 16 fp32 (one thread's 16 contiguous cols) into hi/lo bf16 and write
// to swizzled LDS slots. Row layout: 64 bf16 = 8 slots of 8 elems (16B);
// slot' = slot ^ (row&7). hi -> slots 0..3 (k=0..31), lo -> slots 4..7.
__device__ __forceinline__ void cvtw(unsigned short* rb, int half, int sw,
                                     fx4 d0, fx4 d1, fx4 d2, fx4 d3, float& rsum) {
  float f[16];
#pragma unroll
  for (int i = 0; i < 4; ++i) { f[i] = d0[i]; f[4+i] = d1[i]; f[8+i] = d2[i]; f[12+i] = d3[i]; }
  u8 hv[2], lv[2];
#pragma unroll
  for (int g = 0; g < 2; ++g) {
#pragma unroll
    for (int i = 0; i < 8; ++i) {
      float fv = f[g*8 + i];
      rsum += fv;
      unsigned short h = f2bf(fv);
      hv[g][i] = h;
      lv[g][i] = f2bf(fv - bf2f(h));
    }
  }
#pragma unroll
  for (int g = 0; g < 2; ++g) {
    *(u8*)(rb + (((half*2 + g)     ^ sw) * 8)) = hv[g];
    *(u8*)(rb + (((4 + half*2 + g) ^ sw) * 8)) = lv[g];
  }
}

// G[b] = x[b] x[b]^T via bf16 hi/lo MFMA (HH^T + LH^T + HL^T), split-K atomics.
// Also r[b][c] = sum_n x. One wg = full 256x256 tile, 8 waves of 64x128.
__global__ __launch_bounds__(512) void gram_k(const float* __restrict__ x,
                                              float* __restrict__ G,
                                              float* __restrict__ r) {
  __shared__ unsigned short sb[2][256 * 64];   // 64 KB double-buffered
  const int t = threadIdx.x;
  const int s = blockIdx.x, b = blockIdx.y;
  const int row = t >> 1, half = t & 1;
  const int sw = row & 7;
  const float* xp = x + ((size_t)b * CD + row) * ND + s * GKC + half * 16;
  const int wv = t >> 6, lane = t & 63, l15 = lane & 15, l4 = lane >> 4;
  const int wr = wv >> 1, wc = wv & 1;

  float rsum = 0.f;
  fx4 d0 = *(const fx4*)(xp + 0);
  fx4 d1 = *(const fx4*)(xp + 4);
  fx4 d2 = *(const fx4*)(xp + 8);
  fx4 d3 = *(const fx4*)(xp + 12);

  fx4 acc[4][8];
#pragma unroll
  for (int i = 0; i < 4; ++i)
#pragma unroll
    for (int j = 0; j < 8; ++j)
      acc[i][j] = (fx4){0.f, 0.f, 0.f, 0.f};

  cvtw(&sb[0][row * 64], half, sw, d0, d1, d2, d3, rsum);
  __syncthreads();

#pragma unroll 1
  for (int st = 0; st < GNT; ++st) {
    if (st < GNT - 1) {                 // issue next global loads early
      const float* p = xp + (st + 1) * 32;
      d0 = *(const fx4*)(p + 0);  d1 = *(const fx4*)(p + 4);
      d2 = *(const fx4*)(p + 8);  d3 = *(const fx4*)(p + 12);
    }
    const unsigned short* bp = &sb[st & 1][0];
    s8 aH[4], aL[4];
#pragma unroll
    for (int i = 0; i < 4; ++i) {
      const int R = wr * 64 + i * 16 + l15;
      const int rs = R & 7;
      const unsigned short* rp = bp + R * 64;
      aH[i] = *(const s8*)(rp + ((l4       ^ rs) * 8));
      aL[i] = *(const s8*)(rp + (((4 + l4) ^ rs) * 8));
    }
#pragma unroll
    for (int j = 0; j < 8; ++j) {
      const int Rc = wc * 128 + j * 16 + l15;
      const int rs = Rc & 7;
      const unsigned short* rp = bp + Rc * 64;
      s8 bH = *(const s8*)(rp + ((l4 ^ rs) * 8));
#pragma unroll
      for (int i = 0; i < 4; ++i)
        acc[i][j] = __builtin_amdgcn_mfma_f32_16x16x32_bf16(aH[i], bH, acc[i][j], 0, 0, 0);
#pragma unroll
      for (int i = 0; i < 4; ++i)
        acc[i][j] = __builtin_amdgcn_mfma_f32_16x16x32_bf16(aL[i], bH, acc[i][j], 0, 0, 0);
    }
#pragma unroll
    for (int j = 0; j < 8; ++j) {
      const int Rc = wc * 128 + j * 16 + l15;
      const int rs = Rc & 7;
      const unsigned short* rp = bp + Rc * 64;
      s8 bL = *(const s8*)(rp + (((4 + l4) ^ rs) * 8));
#pragma unroll
      for (int i = 0; i < 4; ++i)
        acc[i][j] = __builtin_amdgcn_mfma_f32_16x16x32_bf16(aH[i], bL, acc[i][j], 0, 0, 0);
    }
    if (st < GNT - 1)
      cvtw(&sb[(st + 1) & 1][row * 64], half, sw, d0, d1, d2, d3, rsum);
    __syncthreads();
  }

  float r2 = rsum + __shfl_down(rsum, 1);
  if ((t & 1) == 0) atomicAdd(&r[b * CD + row], r2);

  float* Gb = G + (size_t)b * CD * CD;
#pragma unroll
  for (int i = 0; i < 4; ++i)
#pragma unroll
    for (int j = 0; j < 8; ++j)
#pragma unroll
      for (int q = 0; q < 4; ++q) {
        const int gr = wr * 64 + i * 16 + l4 * 4 + q;
        const int gc = wc * 128 + j * 16 + l15;
        atomicAdd(&Gb[gr * CD + gc], acc[i][j][q]);
      }
}

// Qt[b][h][dd][c] = sum_m Wq[h*32+dd][m] * G[b][m][c]   (fp32)
__global__ __launch_bounds__(256) void qg_k(const float* __restrict__ Wqkv,
                                            const float* __restrict__ G,
                                            float* __restrict__ Qt) {
  const int cq = blockIdx.x, h = blockIdx.y, b = blockIdx.z;
  const int t = threadIdx.x;
  const int c = cq * 64 + (t & 63);
  const int ms = t >> 6;
  const float* Gb = G + (size_t)b * CD * CD;
  const float* wqb = Wqkv + (size_t)(h * DH) * CD;
  float acc[32];
#pragma unroll
  for (int i = 0; i < 32; ++i) acc[i] = 0.f;
  for (int m = ms * 64; m < ms * 64 + 64; ++m) {
    const float gv = Gb[m * CD + c];
    const float* wq = wqb + m;
#pragma unroll
    for (int dd = 0; dd < 32; ++dd)
      acc[dd] += wq[dd * CD] * gv;
  }
  __shared__ float red[4][32][64];
#pragma unroll
  for (int dd = 0; dd < 32; ++dd) red[ms][dd][t & 63] = acc[dd];
  __syncthreads();
  for (int i = t; i < 32 * 64; i += 256) {
    const int dd = i >> 6, cc = i & 63;
    const float v = red[0][dd][cc] + red[1][dd][cc] + red[2][dd][cc] + red[3][dd][cc];
    Qt[(((size_t)b * NH + h) * DH + dd) * CD + cq * 64 + cc] = v;
  }
}

// S, softmax, and M[o][h*32+e] = sum_dd Wout[o][dd*8+h] * attn[dd][e]
__global__ __launch_bounds__(256) void attn_k(const float* __restrict__ Wqkv,
                                              const float* __restrict__ bqkv,
                                              const float* __restrict__ Wout,
                                              const float* __restrict__ Qt,
                                              const float* __restrict__ r,
                                              float* __restrict__ M) {
  const int h = blockIdx.x, b = blockIdx.y;
  const int t = threadIdx.x;
  __shared__ float S[32][33];
  __shared__ float A[32][33];
  __shared__ float wqr[32], wkr[32];
  const float* rb = r + b * CD;
  if (t < 64) {
    const int dd = t & 31, isk = t >> 5;
    const float* w = Wqkv + (size_t)(isk * CD + h * DH + dd) * CD;
    float sv = 0.f;
    for (int cc = 0; cc < CD; ++cc) sv += w[cc] * rb[cc];
    if (isk) wkr[dd] = sv; else wqr[dd] = sv;
  }
  __syncthreads();
  {
    const int dd = t >> 3;
    const float* q = Qt + (((size_t)b * NH + h) * DH + dd) * CD;
    const float bq = bqkv[h * DH + dd];
#pragma unroll
    for (int u = 0; u < 4; ++u) {
      const int e = (t & 7) * 4 + u;
      const float bk = bqkv[CD + h * DH + e];
      const float* kw = Wqkv + (size_t)(CD + h * DH + e) * CD;
      float sv = 0.f;
      for (int cc = 0; cc < CD; ++cc) sv += q[cc] * kw[cc];
      sv += bq * wkr[e] + bk * wqr[dd] + (float)ND * bq * bk;
      S[dd][e] = sv * SCALE;
    }
  }
  __syncthreads();
  if (t < 32) {
    float mx = -1e30f;
#pragma unroll
    for (int e = 0; e < 32; ++e) mx = fmaxf(mx, S[t][e]);
    float sum = 0.f;
#pragma unroll
    for (int e = 0; e < 32; ++e) sum += __expf(S[t][e] - mx);
    const float inv = 1.f / sum;
#pragma unroll
    for (int e = 0; e < 32; ++e) A[t][e] = __expf(S[t][e] - mx) * inv;
  }
  __syncthreads();
  {
    float wrow[32];
#pragma unroll
    for (int dd = 0; dd < 32; ++dd) wrow[dd] = Wout[(size_t)t * CD + dd * NH + h];
    for (int e = 0; e < 32; ++e) {
      float sv = 0.f;
#pragma unroll
      for (int dd = 0; dd < 32; ++dd) sv += wrow[dd] * A[dd][e];
      M[((size_t)b * CD + t) * CD + h * DH + e] = sv;
    }
  }
}

// P = M @ Wv (store hi/lo bf16), cvec = M @ bv + bout
__global__ __launch_bounds__(256) void pproj_k(const float* __restrict__ Wqkv,
                                               const float* __restrict__ bqkv,
                                               const float* __restrict__ bout,
                                               const float* __restrict__ M,
                                               unsigned short* __restrict__ Ph,
                                               unsigned short* __restrict__ Pl,
                                               float* __restrict__ cvec) {
  const int oq = blockIdx.x, b = blockIdx.y;
  const int t = threadIdx.x;
  const float* Mb = M + (size_t)b * CD * CD + oq * 16 * CD;
  const float* Wv = Wqkv + (size_t)2 * CD * CD;
  float acc[16];
#pragma unroll
  for (int i = 0; i < 16; ++i) acc[i] = 0.f;
  for (int m = 0; m < CD; ++m) {
    const float wvv = Wv[(size_t)m * CD + t];
#pragma unroll
    for (int o = 0; o < 16; ++o) acc[o] += Mb[o * CD + m] * wvv;
  }
#pragma unroll
  for (int o = 0; o < 16; ++o) {
    const int oo = oq * 16 + o;
    const unsigned short hh = f2bf(acc[o]);
    Ph[((size_t)b * CD + oo) * CD + t] = hh;
    Pl[((size_t)b * CD + oo) * CD + t] = f2bf(acc[o] - bf2f(hh));
  }
  if (t < 16) {
    const int oo = oq * 16 + t;
    const float* mr = M + (size_t)b * CD * CD + oo * CD;
    float sv = bout[oo];
    for (int m = 0; m < CD; ++m) sv += mr[m] * bqkv[2 * CD + m];
    cvec[b * CD + oo] = sv;
  }
}

// out[b][o][n] = sum_c (Ph+Pl)[o][c] * bf16(x[b][c][n]) + cvec[b][o]
__global__ __launch_bounds__(512) void out_k(const float* __restrict__ x,
                                             const unsigned short* __restrict__ Ph,
                                             const unsigned short* __restrict__ Pl,
                                             const float* __restrict__ cvec,
                                             float* __restrict__ out) {
  __shared__ unsigned short xT[64][264];   // [n][c], +8 pad => 2-way-free b128 reads
  const int t = threadIdx.x;
  const int nb = blockIdx.x, b = blockIdx.y;
  const int n0 = nb * 64;
  {
    const int nq = (t & 15) * 4;
    const int cg = t >> 4;                 // 0..31
#pragma unroll
    for (int it = 0; it < 8; ++it) {
      const int c = it * 32 + cg;
      const float* p = x + ((size_t)b * CD + c) * ND + n0 + nq;
      fx4 v = *(const fx4*)p;
      xT[nq + 0][c] = f2bf(v[0]);
      xT[nq + 1][c] = f2bf(v[1]);
      xT[nq + 2][c] = f2bf(v[2]);
      xT[nq + 3][c] = f2bf(v[3]);
    }
  }
  __syncthreads();
  const int wv = t >> 6, lane = t & 63, l15 = lane & 15, l4 = lane >> 4;
  const int wr = wv >> 1, wc = wv & 1;
  fx4 acc[4][2];
#pragma unroll
  for (int i = 0; i < 4; ++i) { acc[i][0] = (fx4){0,0,0,0}; acc[i][1] = (fx4){0,0,0,0}; }
#pragma unroll 1
  for (int st = 0; st < 16; ++st) {
    const unsigned short* Ap = (st < 8 ? Ph : Pl) + (size_t)b * CD * CD;
    const int kc = (st & 7) * 32 + l4 * 8;
    s8 af[4];
#pragma unroll
    for (int i = 0; i < 4; ++i) {
      const int o = wr * 64 + i * 16 + l15;
      af[i] = *(const s8*)(Ap + (size_t)o * CD + kc);
    }
#pragma unroll
    for (int j = 0; j < 2; ++j) {
      const int n = wc * 32 + j * 16 + l15;
      s8 bf_ = *(const s8*)(&xT[n][kc]);
#pragma unroll
      for (int i = 0; i < 4; ++i)
        acc[i][j] = __builtin_amdgcn_mfma_f32_16x16x32_bf16(af[i], bf_, acc[i][j], 0, 0, 0);
    }
  }
  const float* cp = cvec + b * CD;
  float* ob = out + (size_t)b * CD * ND + n0;
#pragma unroll
  for (int i = 0; i < 4; ++i)
#pragma unroll
    for (int q = 0; q < 4; ++q) {
      const int o = wr * 64 + i * 16 + l4 * 4 + q;
      const float ad = cp[o];
#pragma unroll
      for (int j = 0; j < 2; ++j) {
        const int n = wc * 32 + j * 16 + l15;
        ob[(size_t)o * ND + n] = acc[i][j][q] + ad;
      }
    }
}

extern "C" void kernel_launch(void* const* d_in, const int* in_sizes, int n_in,
                              void* d_out, int out_size, void* d_ws, size_t ws_size,
                              hipStream_t stream) {
  const float* x    = (const float*)d_in[0];
  const float* Wqkv = (const float*)d_in[1];
  const float* bqkv = (const float*)d_in[2];
  const float* Wout = (const float*)d_in[3];
  const float* bout = (const float*)d_in[4];
  float* out = (float*)d_out;

  char* ws = (char*)d_ws;
  float*          G    = (float*)(ws + 0);                // 2 MB
  float*          r    = (float*)(ws + 2097152);          // 8 KB
  float*          Mm   = (float*)(ws + 2105344);          // 2 MB
  unsigned short* Ph   = (unsigned short*)(ws + 4202496); // 1 MB
  unsigned short* Pl   = (unsigned short*)(ws + 5251072); // 1 MB
  float*          cvec = (float*)(ws + 6299648);          // 8 KB
  float*          Qt   = (float*)(ws + 6307840);          // 2 MB (total ~8.4 MB)

  hipMemsetAsync(ws, 0, 2105344, stream);  // zero G and r (atomic targets)

  gram_k <<<dim3(GSPLIT, BD), 512, 0, stream>>>(x, G, r);
  qg_k   <<<dim3(4, NH, BD),  256, 0, stream>>>(Wqkv, G, Qt);
  attn_k <<<dim3(NH, BD),     256, 0, stream>>>(Wqkv, bqkv, Wout, Qt, r, Mm);
  pproj_k<<<dim3(16, BD),     256, 0, stream>>>(Wqkv, bqkv, bout, Mm, Ph, Pl, cvec);
  out_k  <<<dim3(ND / 64, BD), 512, 0, stream>>>(x, Ph, Pl, cvec, out);
}

// Round 2
// 319.732 us; speedup vs baseline: 1.1042x; 1.1042x over previous
//
#include <hip/hip_runtime.h>

typedef __attribute__((ext_vector_type(4))) float  fx4;
typedef __attribute__((ext_vector_type(8))) short  s8;
typedef __attribute__((ext_vector_type(8))) unsigned short u8;

#define BD   8
#define CD   256
#define ND   16384
#define NH   8
#define DH   32
#define SCALE 0.17677669529663687f   // 1/sqrt(32)

#define GSPLIT 64
#define GKC (ND / GSPLIT)   // 256 fp32 cols per workgroup
#define GNT (GKC / 32)      // 8 K-steps of 32 fp32 cols

__device__ __forceinline__ unsigned short f2bf(float f) {
  unsigned int u = __float_as_uint(f);
  u += 0x7fffu + ((u >> 16) & 1u);      // RNE
  return (unsigned short)(u >> 16);
}
__device__ __forceinline__ float bf2f(unsigned short b) {
  return __uint_as_float(((unsigned int)b) << 16);
}

// convert 16 fp32 (one thread's 16 contiguous cols) into hi/lo bf16 and write
// to swizzled LDS slots. Row layout: 64 bf16 = 8 slots of 8 elems (16B);
// slot' = slot ^ (row&7). hi -> slots 0..3 (k=0..31), lo -> slots 4..7.
__device__ __forceinline__ void cvtw(unsigned short* rb, int half, int sw,
                                     fx4 d0, fx4 d1, fx4 d2, fx4 d3, float& rsum) {
  float f[16];
#pragma unroll
  for (int i = 0; i < 4; ++i) { f[i] = d0[i]; f[4+i] = d1[i]; f[8+i] = d2[i]; f[12+i] = d3[i]; }
  u8 hv[2], lv[2];
#pragma unroll
  for (int g = 0; g < 2; ++g) {
#pragma unroll
    for (int i = 0; i < 8; ++i) {
      float fv = f[g*8 + i];
      rsum += fv;
      unsigned short h = f2bf(fv);
      hv[g][i] = h;
      lv[g][i] = f2bf(fv - bf2f(h));
    }
  }
#pragma unroll
  for (int g = 0; g < 2; ++g) {
    *(u8*)(rb + (((half*2 + g)     ^ sw) * 8)) = hv[g];
    *(u8*)(rb + (((4 + half*2 + g) ^ sw) * 8)) = lv[g];
  }
}

// G[b] = x[b] x[b]^T via bf16 hi/lo MFMA (HH^T + LH^T + HL^T), split-K atomics.
// Also r[b][c] = sum_n x. One wg = full 256x256 tile, 8 waves of 64x128.
__global__ __launch_bounds__(512) void gram_k(const float* __restrict__ x,
                                              float* __restrict__ G,
                                              float* __restrict__ r) {
  __shared__ unsigned short sb[2][256 * 64];   // 64 KB double-buffered
  const int t = threadIdx.x;
  const int s = blockIdx.x, b = blockIdx.y;
  const int row = t >> 1, half = t & 1;
  const int sw = row & 7;
  const float* xp = x + ((size_t)b * CD + row) * ND + s * GKC + half * 16;
  const int wv = t >> 6, lane = t & 63, l15 = lane & 15, l4 = lane >> 4;
  const int wr = wv >> 1, wc = wv & 1;

  float rsum = 0.f;
  fx4 d0 = *(const fx4*)(xp + 0);
  fx4 d1 = *(const fx4*)(xp + 4);
  fx4 d2 = *(const fx4*)(xp + 8);
  fx4 d3 = *(const fx4*)(xp + 12);

  fx4 acc[4][8];
#pragma unroll
  for (int i = 0; i < 4; ++i)
#pragma unroll
    for (int j = 0; j < 8; ++j)
      acc[i][j] = (fx4){0.f, 0.f, 0.f, 0.f};

  cvtw(&sb[0][row * 64], half, sw, d0, d1, d2, d3, rsum);
  __syncthreads();

#pragma unroll 1
  for (int st = 0; st < GNT; ++st) {
    if (st < GNT - 1) {                 // issue next global loads early
      const float* p = xp + (st + 1) * 32;
      d0 = *(const fx4*)(p + 0);  d1 = *(const fx4*)(p + 4);
      d2 = *(const fx4*)(p + 8);  d3 = *(const fx4*)(p + 12);
    }
    const unsigned short* bp = &sb[st & 1][0];
    s8 aH[4], aL[4];
#pragma unroll
    for (int i = 0; i < 4; ++i) {
      const int R = wr * 64 + i * 16 + l15;
      const int rs = R & 7;
      const unsigned short* rp = bp + R * 64;
      aH[i] = *(const s8*)(rp + ((l4       ^ rs) * 8));
      aL[i] = *(const s8*)(rp + (((4 + l4) ^ rs) * 8));
    }
#pragma unroll
    for (int j = 0; j < 8; ++j) {
      const int Rc = wc * 128 + j * 16 + l15;
      const int rs = Rc & 7;
      const unsigned short* rp = bp + Rc * 64;
      s8 bH = *(const s8*)(rp + ((l4 ^ rs) * 8));
#pragma unroll
      for (int i = 0; i < 4; ++i)
        acc[i][j] = __builtin_amdgcn_mfma_f32_16x16x32_bf16(aH[i], bH, acc[i][j], 0, 0, 0);
#pragma unroll
      for (int i = 0; i < 4; ++i)
        acc[i][j] = __builtin_amdgcn_mfma_f32_16x16x32_bf16(aL[i], bH, acc[i][j], 0, 0, 0);
    }
#pragma unroll
    for (int j = 0; j < 8; ++j) {
      const int Rc = wc * 128 + j * 16 + l15;
      const int rs = Rc & 7;
      const unsigned short* rp = bp + Rc * 64;
      s8 bL = *(const s8*)(rp + (((4 + l4) ^ rs) * 8));
#pragma unroll
      for (int i = 0; i < 4; ++i)
        acc[i][j] = __builtin_amdgcn_mfma_f32_16x16x32_bf16(aH[i], bL, acc[i][j], 0, 0, 0);
    }
    if (st < GNT - 1)
      cvtw(&sb[(st + 1) & 1][row * 64], half, sw, d0, d1, d2, d3, rsum);
    __syncthreads();
  }

  float r2 = rsum + __shfl_down(rsum, 1);
  if ((t & 1) == 0) atomicAdd(&r[b * CD + row], r2);

  float* Gb = G + (size_t)b * CD * CD;
#pragma unroll
  for (int i = 0; i < 4; ++i)
#pragma unroll
    for (int j = 0; j < 8; ++j)
#pragma unroll
      for (int q = 0; q < 4; ++q) {
        const int gr = wr * 64 + i * 16 + l4 * 4 + q;
        const int gc = wc * 128 + j * 16 + l15;
        atomicAdd(&Gb[gr * CD + gc], acc[i][j][q]);
      }
}

// Qt[b][h][dd][c] = sum_m Wq[h*32+dd][m] * G[b][m][c]   (fp32)
__global__ __launch_bounds__(256) void qg_k(const float* __restrict__ Wqkv,
                                            const float* __restrict__ G,
                                            float* __restrict__ Qt) {
  const int cq = blockIdx.x, h = blockIdx.y, b = blockIdx.z;
  const int t = threadIdx.x;
  const int c = cq * 64 + (t & 63);
  const int ms = t >> 6;
  const float* Gb = G + (size_t)b * CD * CD;
  const float* wqb = Wqkv + (size_t)(h * DH) * CD;
  float acc[32];
#pragma unroll
  for (int i = 0; i < 32; ++i) acc[i] = 0.f;
  for (int m = ms * 64; m < ms * 64 + 64; ++m) {
    const float gv = Gb[m * CD + c];
    const float* wq = wqb + m;
#pragma unroll
    for (int dd = 0; dd < 32; ++dd)
      acc[dd] += wq[dd * CD] * gv;
  }
  __shared__ float red[4][32][64];
#pragma unroll
  for (int dd = 0; dd < 32; ++dd) red[ms][dd][t & 63] = acc[dd];
  __syncthreads();
  for (int i = t; i < 32 * 64; i += 256) {
    const int dd = i >> 6, cc = i & 63;
    const float v = red[0][dd][cc] + red[1][dd][cc] + red[2][dd][cc] + red[3][dd][cc];
    Qt[(((size_t)b * NH + h) * DH + dd) * CD + cq * 64 + cc] = v;
  }
}

// S, softmax, and M[o][h*32+e] = sum_dd Wout[o][dd*8+h] * attn[dd][e]
__global__ __launch_bounds__(256) void attn_k(const float* __restrict__ Wqkv,
                                              const float* __restrict__ bqkv,
                                              const float* __restrict__ Wout,
                                              const float* __restrict__ Qt,
                                              const float* __restrict__ r,
                                              float* __restrict__ M) {
  const int h = blockIdx.x, b = blockIdx.y;
  const int t = threadIdx.x;
  __shared__ float S[32][33];
  __shared__ float A[32][33];
  __shared__ float wqr[32], wkr[32];
  __shared__ float wred[64][4];
  const float* rb = r + b * CD;
  {
    const int rowid = t & 63;            // (isk<<5)|dd
    const int q = t >> 6;                // quarter of the 256-c dot
    const int isk = rowid >> 5, dd = rowid & 31;
    const float* w = Wqkv + (size_t)(isk * CD + h * DH + dd) * CD + q * 64;
    const float* rq = rb + q * 64;
    float sv = 0.f;
#pragma unroll
    for (int cc = 0; cc < 64; ++cc) sv += w[cc] * rq[cc];
    wred[rowid][q] = sv;
  }
  __syncthreads();
  if (t < 64) {
    const float sv = wred[t][0] + wred[t][1] + wred[t][2] + wred[t][3];
    if (t >> 5) wkr[t & 31] = sv; else wqr[t & 31] = sv;
  }
  __syncthreads();
  {
    const int dd = t >> 3;
    const float* q = Qt + (((size_t)b * NH + h) * DH + dd) * CD;
    const float bq = bqkv[h * DH + dd];
#pragma unroll
    for (int u = 0; u < 4; ++u) {
      const int e = (t & 7) * 4 + u;
      const float bk = bqkv[CD + h * DH + e];
      const float* kw = Wqkv + (size_t)(CD + h * DH + e) * CD;
      float sv = 0.f;
      for (int cc = 0; cc < CD; ++cc) sv += q[cc] * kw[cc];
      sv += bq * wkr[e] + bk * wqr[dd] + (float)ND * bq * bk;
      S[dd][e] = sv * SCALE;
    }
  }
  __syncthreads();
  if (t < 32) {
    float mx = -1e30f;
#pragma unroll
    for (int e = 0; e < 32; ++e) mx = fmaxf(mx, S[t][e]);
    float sum = 0.f;
#pragma unroll
    for (int e = 0; e < 32; ++e) sum += __expf(S[t][e] - mx);
    const float inv = 1.f / sum;
#pragma unroll
    for (int e = 0; e < 32; ++e) A[t][e] = __expf(S[t][e] - mx) * inv;
  }
  __syncthreads();
  {
    float wrow[32];
#pragma unroll
    for (int dd = 0; dd < 32; ++dd) wrow[dd] = Wout[(size_t)t * CD + dd * NH + h];
    for (int e = 0; e < 32; ++e) {
      float sv = 0.f;
#pragma unroll
      for (int dd = 0; dd < 32; ++dd) sv += wrow[dd] * A[dd][e];
      M[((size_t)b * CD + t) * CD + h * DH + e] = sv;
    }
  }
}

// P = M @ Wv stored bf16 in MFMA-fragment order Pf[b][kq][o][8] (kq = c>>3),
// cvec = M @ bv + bout. (Pl dropped: |Pl.x| ~ 1e-3, within error budget.)
__global__ __launch_bounds__(256) void pproj_k(const float* __restrict__ Wqkv,
                                               const float* __restrict__ bqkv,
                                               const float* __restrict__ bout,
                                               const float* __restrict__ M,
                                               unsigned short* __restrict__ Pf,
                                               float* __restrict__ cvec) {
  const int oq = blockIdx.x, b = blockIdx.y;
  const int t = threadIdx.x;                 // t = c
  const float* Mb = M + (size_t)b * CD * CD + oq * 16 * CD;
  const float* Wv = Wqkv + (size_t)2 * CD * CD;
  float acc[16];
#pragma unroll
  for (int i = 0; i < 16; ++i) acc[i] = 0.f;
  for (int m = 0; m < CD; ++m) {
    const float wvv = Wv[(size_t)m * CD + t];
#pragma unroll
    for (int o = 0; o < 16; ++o) acc[o] += Mb[o * CD + m] * wvv;
  }
#pragma unroll
  for (int o = 0; o < 16; ++o) {
    const int oo = oq * 16 + o;
    Pf[(((size_t)b * 32 + (t >> 3)) * 256 + oo) * 8 + (t & 7)] = f2bf(acc[o]);
  }
  if (t < 16) {
    const int oo = oq * 16 + t;
    const float* mr = M + (size_t)b * CD * CD + oo * CD;
    float sv = bout[oo];
    for (int m = 0; m < CD; ++m) sv += mr[m] * bqkv[2 * CD + m];
    cvec[b * CD + oo] = sv;
  }
}

// out[b][o][n] = sum_c P[o][c] * bf16(x[b][c][n]) + cvec[b][o]
// Tile: 256 o x 128 n, K=256 fully LDS-resident -> barrier-free K-loop.
// xT LDS layout: row n (512 B) of 32 16-B slots, slot' = (c>>3) ^ (n&15).
__global__ __launch_bounds__(512) void out_k(const float* __restrict__ x,
                                             const unsigned short* __restrict__ Pf,
                                             const float* __restrict__ cvec,
                                             float* __restrict__ out) {
  __shared__ unsigned short xT[128 * 256];   // 64 KB
  const int t = threadIdx.x;
  const int nb = blockIdx.x, b = blockIdx.y;
  const int n0 = nb * 128;
  const int w = t >> 6, l = t & 63, l15 = l & 15, l4 = l >> 4;

  // ---- staging: coalesced row loads + thread-local 4x4 transpose ----
  {
    const int nbase = (w & 1) * 64 + l15 * 4;     // n-offset within tile
    const int cb0   = (w >> 1) * 16 + l4 * 4;     // c-base before it*64
#pragma unroll
    for (int it = 0; it < 4; ++it) {
      const int cb = cb0 + it * 64;
      const float* p = x + ((size_t)b * CD + cb) * ND + n0 + nbase;
      fx4 r0 = *(const fx4*)(p);
      fx4 r1 = *(const fx4*)(p + ND);
      fx4 r2 = *(const fx4*)(p + 2 * (size_t)ND);
      fx4 r3 = *(const fx4*)(p + 3 * (size_t)ND);
#pragma unroll
      for (int j = 0; j < 4; ++j) {
        const unsigned long long wlo =
            (unsigned long long)f2bf(r0[j]) |
            ((unsigned long long)f2bf(r1[j]) << 16) |
            ((unsigned long long)f2bf(r2[j]) << 32) |
            ((unsigned long long)f2bf(r3[j]) << 48);
        const int n = nbase + j;
        const int slot = ((cb >> 3) ^ (n & 15)) & 31;
        *(unsigned long long*)(&xT[n * 256 + slot * 8 + (cb & 7)]) = wlo;
      }
    }
  }
  __syncthreads();

  // ---- K loop: 8 steps of K=32, no barriers ----
  const int wr = w >> 1, wc = w & 1;   // 4 o-blocks x 2 n-blocks
  fx4 acc[4][4];
#pragma unroll
  for (int i = 0; i < 4; ++i)
#pragma unroll
    for (int j = 0; j < 4; ++j) acc[i][j] = (fx4){0.f, 0.f, 0.f, 0.f};

  const unsigned short* Pb = Pf + (size_t)b * 32 * 256 * 8;
  s8 afc[4], afn[4];
#pragma unroll
  for (int i = 0; i < 4; ++i) {
    const int o = wr * 64 + i * 16 + l15;
    afc[i] = *(const s8*)(Pb + ((size_t)(l4) * 256 + o) * 8);
  }
#pragma unroll
  for (int st = 0; st < 8; ++st) {
    if (st < 7) {
      const int kq = (st + 1) * 4 + l4;
#pragma unroll
      for (int i = 0; i < 4; ++i) {
        const int o = wr * 64 + i * 16 + l15;
        afn[i] = *(const s8*)(Pb + ((size_t)kq * 256 + o) * 8);
      }
    }
#pragma unroll
    for (int j = 0; j < 4; ++j) {
      const int n = wc * 64 + j * 16 + l15;
      const int slot = ((st * 4 + l4) ^ (n & 15)) & 31;
      s8 bf_ = *(const s8*)(&xT[n * 256 + slot * 8]);
#pragma unroll
      for (int i = 0; i < 4; ++i)
        acc[i][j] = __builtin_amdgcn_mfma_f32_16x16x32_bf16(afc[i], bf_, acc[i][j], 0, 0, 0);
    }
#pragma unroll
    for (int i = 0; i < 4; ++i) afc[i] = afn[i];
  }

  // ---- epilogue ----
  const float* cp = cvec + b * CD;
  float* ob = out + (size_t)b * CD * ND + n0;
#pragma unroll
  for (int i = 0; i < 4; ++i)
#pragma unroll
    for (int q = 0; q < 4; ++q) {
      const int o = wr * 64 + i * 16 + l4 * 4 + q;
      const float ad = cp[o];
#pragma unroll
      for (int j = 0; j < 4; ++j) {
        const int n = wc * 64 + j * 16 + l15;
        ob[(size_t)o * ND + n] = acc[i][j][q] + ad;
      }
    }
}

extern "C" void kernel_launch(void* const* d_in, const int* in_sizes, int n_in,
                              void* d_out, int out_size, void* d_ws, size_t ws_size,
                              hipStream_t stream) {
  const float* x    = (const float*)d_in[0];
  const float* Wqkv = (const float*)d_in[1];
  const float* bqkv = (const float*)d_in[2];
  const float* Wout = (const float*)d_in[3];
  const float* bout = (const float*)d_in[4];
  float* out = (float*)d_out;

  char* ws = (char*)d_ws;
  float*          G    = (float*)(ws + 0);                // 2 MB
  float*          r    = (float*)(ws + 2097152);          // 8 KB
  float*          Mm   = (float*)(ws + 2105344);          // 2 MB
  unsigned short* Pf   = (unsigned short*)(ws + 4202496); // 1 MB
  float*          cvec = (float*)(ws + 6299648);          // 8 KB
  float*          Qt   = (float*)(ws + 6307840);          // 2 MB (total ~8.4 MB)

  hipMemsetAsync(ws, 0, 2105344, stream);  // zero G and r (atomic targets)

  gram_k <<<dim3(GSPLIT, BD), 512, 0, stream>>>(x, G, r);
  qg_k   <<<dim3(4, NH, BD),  256, 0, stream>>>(Wqkv, G, Qt);
  attn_k <<<dim3(NH, BD),     256, 0, stream>>>(Wqkv, bqkv, Wout, Qt, r, Mm);
  pproj_k<<<dim3(16, BD),     256, 0, stream>>>(Wqkv, bqkv, bout, Mm, Pf, cvec);
  out_k  <<<dim3(ND / 128, BD), 512, 0, stream>>>(x, Pf, cvec, out);
}

// Round 3
// 245.866 us; speedup vs baseline: 1.4360x; 1.3004x over previous
//
#include <hip/hip_runtime.h>

typedef __attribute__((ext_vector_type(4))) float  fx4;
typedef __attribute__((ext_vector_type(8))) short  s8;
typedef __attribute__((ext_vector_type(8))) unsigned short u8;

#define BD   8
#define CD   256
#define ND   16384
#define NH   8
#define DH   32
#define SCALE 0.17677669529663687f   // 1/sqrt(32)

#define GS    16            // split-K factor
#define GKB   (ND / GS)     // 1024 fp32 cols per block
#define GNSTEP (GKB / 32)   // 32 K-steps of 32 cols

__device__ __forceinline__ unsigned short f2bf(float f) {
  unsigned int u = __float_as_uint(f);
  u += 0x7fffu + ((u >> 16) & 1u);      // RNE
  return (unsigned short)(u >> 16);
}
__device__ __forceinline__ float bf2f(unsigned short b) {
  return __uint_as_float(((unsigned int)b) << 16);
}

// convert 16 fp32 (one thread's 16 contiguous cols) into hi/lo bf16 and write
// to swizzled LDS slots. Row layout: 64 bf16 = 8 slots of 8 elems (16B);
// slot' = slot ^ (row&7). hi -> slots 0..3 (k=0..31), lo -> slots 4..7.
__device__ __forceinline__ void cvtw(unsigned short* rb, int half, int sw,
                                     fx4 d0, fx4 d1, fx4 d2, fx4 d3, float& rsum) {
  float f[16];
#pragma unroll
  for (int i = 0; i < 4; ++i) { f[i] = d0[i]; f[4+i] = d1[i]; f[8+i] = d2[i]; f[12+i] = d3[i]; }
  u8 hv[2], lv[2];
#pragma unroll
  for (int g = 0; g < 2; ++g) {
#pragma unroll
    for (int i = 0; i < 8; ++i) {
      float fv = f[g*8 + i];
      rsum += fv;
      unsigned short h = f2bf(fv);
      hv[g][i] = h;
      lv[g][i] = f2bf(fv - bf2f(h));
    }
  }
#pragma unroll
  for (int g = 0; g < 2; ++g) {
    *(u8*)(rb + (((half*2 + g)     ^ sw) * 8)) = hv[g];
    *(u8*)(rb + (((4 + half*2 + g) ^ sw) * 8)) = lv[g];
  }
}

// G = x x^T via bf16 hi/lo MFMA (HH^T + LH^T + HL^T).
// Block (s, rh, b): G rows [rh*128, rh*128+128) x all 256 cols, K-slab s.
// Partial mode: plain stores to Gpart[b][s]; atomic mode: atomicAdd into Gsum.
// Also r[b][c] = sum_n x (rh==0 blocks only).
__global__ __launch_bounds__(512) void gram_k(const float* __restrict__ x,
                                              float* __restrict__ Gdst,
                                              float* __restrict__ r,
                                              int atomic_mode) {
  __shared__ unsigned short sb[2][256 * 64];   // 64 KB double-buffered
  const int t = threadIdx.x;
  const int s = blockIdx.x, rh = blockIdx.y, b = blockIdx.z;
  const int row = t >> 1, half = t & 1;
  const int sw = row & 7;
  const float* xp = x + ((size_t)b * CD + row) * ND + s * GKB + half * 16;
  const int wv = t >> 6, lane = t & 63, l15 = lane & 15, l4 = lane >> 4;
  const int wr = wv >> 2, wc = wv & 3;   // 2 row-groups x 4 col-groups

  float rsum = 0.f;
  fx4 d0 = *(const fx4*)(xp + 0);
  fx4 d1 = *(const fx4*)(xp + 4);
  fx4 d2 = *(const fx4*)(xp + 8);
  fx4 d3 = *(const fx4*)(xp + 12);

  fx4 acc[4][4];
#pragma unroll
  for (int i = 0; i < 4; ++i)
#pragma unroll
    for (int j = 0; j < 4; ++j)
      acc[i][j] = (fx4){0.f, 0.f, 0.f, 0.f};

  cvtw(&sb[0][row * 64], half, sw, d0, d1, d2, d3, rsum);
  __syncthreads();

#pragma unroll 1
  for (int st = 0; st < GNSTEP; ++st) {
    if (st < GNSTEP - 1) {              // issue next global loads early
      const float* p = xp + (st + 1) * 32;
      d0 = *(const fx4*)(p + 0);  d1 = *(const fx4*)(p + 4);
      d2 = *(const fx4*)(p + 8);  d3 = *(const fx4*)(p + 12);
    }
    const unsigned short* bp = &sb[st & 1][0];
    s8 aH[4], aL[4], bH[4], bL[4];
#pragma unroll
    for (int i = 0; i < 4; ++i) {
      const int R = rh * 128 + wr * 64 + i * 16 + l15;
      const int rs = R & 7;
      const unsigned short* rp = bp + R * 64;
      aH[i] = *(const s8*)(rp + ((l4       ^ rs) * 8));
      aL[i] = *(const s8*)(rp + (((4 + l4) ^ rs) * 8));
    }
#pragma unroll
    for (int j = 0; j < 4; ++j) {
      const int Rc = wc * 64 + j * 16 + l15;
      const int rs = Rc & 7;
      const unsigned short* rp = bp + Rc * 64;
      bH[j] = *(const s8*)(rp + ((l4       ^ rs) * 8));
      bL[j] = *(const s8*)(rp + (((4 + l4) ^ rs) * 8));
    }
#pragma unroll
    for (int j = 0; j < 4; ++j)
#pragma unroll
      for (int i = 0; i < 4; ++i)
        acc[i][j] = __builtin_amdgcn_mfma_f32_16x16x32_bf16(aH[i], bH[j], acc[i][j], 0, 0, 0);
#pragma unroll
    for (int j = 0; j < 4; ++j)
#pragma unroll
      for (int i = 0; i < 4; ++i)
        acc[i][j] = __builtin_amdgcn_mfma_f32_16x16x32_bf16(aL[i], bH[j], acc[i][j], 0, 0, 0);
#pragma unroll
    for (int j = 0; j < 4; ++j)
#pragma unroll
      for (int i = 0; i < 4; ++i)
        acc[i][j] = __builtin_amdgcn_mfma_f32_16x16x32_bf16(aH[i], bL[j], acc[i][j], 0, 0, 0);
    if (st < GNSTEP - 1)
      cvtw(&sb[(st + 1) & 1][row * 64], half, sw, d0, d1, d2, d3, rsum);
    __syncthreads();
  }

  if (rh == 0) {
    float r2 = rsum + __shfl_down(rsum, 1);
    if ((t & 1) == 0) atomicAdd(&r[b * CD + row], r2);
  }

  if (atomic_mode) {
    float* Gb = Gdst + (size_t)b * CD * CD;
#pragma unroll
    for (int i = 0; i < 4; ++i)
#pragma unroll
      for (int j = 0; j < 4; ++j)
#pragma unroll
        for (int q = 0; q < 4; ++q) {
          const int gr = rh * 128 + wr * 64 + i * 16 + l4 * 4 + q;
          const int gc = wc * 64 + j * 16 + l15;
          atomicAdd(&Gb[gr * CD + gc], acc[i][j][q]);
        }
  } else {
    float* Gb = Gdst + ((size_t)(b * GS + s)) * CD * CD;
#pragma unroll
    for (int i = 0; i < 4; ++i)
#pragma unroll
      for (int j = 0; j < 4; ++j)
#pragma unroll
        for (int q = 0; q < 4; ++q) {
          const int gr = rh * 128 + wr * 64 + i * 16 + l4 * 4 + q;
          const int gc = wc * 64 + j * 16 + l15;
          Gb[gr * CD + gc] = acc[i][j][q];
        }
  }
}

// Gsum[b] = sum_s Gpart[b][s]   (streaming fx4)
__global__ __launch_bounds__(256) void reduce_k(const float* __restrict__ Gpart,
                                                float* __restrict__ Gsum) {
  const int gid = blockIdx.x * 256 + threadIdx.x;   // 131072 fx4 total
  const int b = gid >> 14;                          // 16384 fx4 per batch
  const int e = gid & 16383;
  const float* p = Gpart + (size_t)b * GS * 65536 + (size_t)e * 4;
  fx4 sv = (fx4){0.f, 0.f, 0.f, 0.f};
#pragma unroll
  for (int k = 0; k < GS; ++k)
    sv += *(const fx4*)(p + (size_t)k * 65536);
  *(fx4*)(Gsum + (size_t)b * 65536 + (size_t)e * 4) = sv;
}

// Qt[b][h][dd][c] = sum_m Wq[h*32+dd][m] * G[b][m][c]   (fp32)
__global__ __launch_bounds__(256) void qg_k(const float* __restrict__ Wqkv,
                                            const float* __restrict__ G,
                                            float* __restrict__ Qt) {
  const int cq = blockIdx.x, h = blockIdx.y, b = blockIdx.z;
  const int t = threadIdx.x;
  const int c = cq * 64 + (t & 63);
  const int ms = t >> 6;
  const float* Gb = G + (size_t)b * CD * CD;
  const float* wqb = Wqkv + (size_t)(h * DH) * CD;
  float acc[32];
#pragma unroll
  for (int i = 0; i < 32; ++i) acc[i] = 0.f;
  for (int m = ms * 64; m < ms * 64 + 64; ++m) {
    const float gv = Gb[m * CD + c];
    const float* wq = wqb + m;
#pragma unroll
    for (int dd = 0; dd < 32; ++dd)
      acc[dd] += wq[dd * CD] * gv;
  }
  __shared__ float red[4][32][64];
#pragma unroll
  for (int dd = 0; dd < 32; ++dd) red[ms][dd][t & 63] = acc[dd];
  __syncthreads();
  for (int i = t; i < 32 * 64; i += 256) {
    const int dd = i >> 6, cc = i & 63;
    const float v = red[0][dd][cc] + red[1][dd][cc] + red[2][dd][cc] + red[3][dd][cc];
    Qt[(((size_t)b * NH + h) * DH + dd) * CD + cq * 64 + cc] = v;
  }
}

// S, softmax, and M[o][h*32+e] = sum_dd Wout[o][dd*8+h] * attn[dd][e]
__global__ __launch_bounds__(256) void attn_k(const float* __restrict__ Wqkv,
                                              const float* __restrict__ bqkv,
                                              const float* __restrict__ Wout,
                                              const float* __restrict__ Qt,
                                              const float* __restrict__ r,
                                              float* __restrict__ M) {
  const int h = blockIdx.x, b = blockIdx.y;
  const int t = threadIdx.x;
  __shared__ float S[32][33];
  __shared__ float A[32][33];
  __shared__ float wqr[32], wkr[32];
  __shared__ float wred[64][4];
  const float* rb = r + b * CD;
  {
    const int rowid = t & 63;            // (isk<<5)|dd
    const int q = t >> 6;                // quarter of the 256-c dot
    const int isk = rowid >> 5, dd = rowid & 31;
    const float* w = Wqkv + (size_t)(isk * CD + h * DH + dd) * CD + q * 64;
    const float* rq = rb + q * 64;
    float sv = 0.f;
#pragma unroll
    for (int cc = 0; cc < 64; ++cc) sv += w[cc] * rq[cc];
    wred[rowid][q] = sv;
  }
  __syncthreads();
  if (t < 64) {
    const float sv = wred[t][0] + wred[t][1] + wred[t][2] + wred[t][3];
    if (t >> 5) wkr[t & 31] = sv; else wqr[t & 31] = sv;
  }
  __syncthreads();
  {
    const int dd = t >> 3;
    const float* q = Qt + (((size_t)b * NH + h) * DH + dd) * CD;
    const float bq = bqkv[h * DH + dd];
#pragma unroll
    for (int u = 0; u < 4; ++u) {
      const int e = (t & 7) * 4 + u;
      const float bk = bqkv[CD + h * DH + e];
      const float* kw = Wqkv + (size_t)(CD + h * DH + e) * CD;
      float sv = 0.f;
      for (int cc = 0; cc < CD; ++cc) sv += q[cc] * kw[cc];
      sv += bq * wkr[e] + bk * wqr[dd] + (float)ND * bq * bk;
      S[dd][e] = sv * SCALE;
    }
  }
  __syncthreads();
  if (t < 32) {
    float mx = -1e30f;
#pragma unroll
    for (int e = 0; e < 32; ++e) mx = fmaxf(mx, S[t][e]);
    float sum = 0.f;
#pragma unroll
    for (int e = 0; e < 32; ++e) sum += __expf(S[t][e] - mx);
    const float inv = 1.f / sum;
#pragma unroll
    for (int e = 0; e < 32; ++e) A[t][e] = __expf(S[t][e] - mx) * inv;
  }
  __syncthreads();
  {
    float wrow[32];
#pragma unroll
    for (int dd = 0; dd < 32; ++dd) wrow[dd] = Wout[(size_t)t * CD + dd * NH + h];
    for (int e = 0; e < 32; ++e) {
      float sv = 0.f;
#pragma unroll
      for (int dd = 0; dd < 32; ++dd) sv += wrow[dd] * A[dd][e];
      M[((size_t)b * CD + t) * CD + h * DH + e] = sv;
    }
  }
}

// P = M @ Wv stored bf16 in MFMA-fragment order Pf[b][kq][o][8] (kq = c>>3),
// cvec = M @ bv + bout.
__global__ __launch_bounds__(256) void pproj_k(const float* __restrict__ Wqkv,
                                               const float* __restrict__ bqkv,
                                               const float* __restrict__ bout,
                                               const float* __restrict__ M,
                                               unsigned short* __restrict__ Pf,
                                               float* __restrict__ cvec) {
  const int oq = blockIdx.x, b = blockIdx.y;
  const int t = threadIdx.x;                 // t = c
  const float* Mb = M + (size_t)b * CD * CD + oq * 16 * CD;
  const float* Wv = Wqkv + (size_t)2 * CD * CD;
  float acc[16];
#pragma unroll
  for (int i = 0; i < 16; ++i) acc[i] = 0.f;
  for (int m = 0; m < CD; ++m) {
    const float wvv = Wv[(size_t)m * CD + t];
#pragma unroll
    for (int o = 0; o < 16; ++o) acc[o] += Mb[o * CD + m] * wvv;
  }
#pragma unroll
  for (int o = 0; o < 16; ++o) {
    const int oo = oq * 16 + o;
    Pf[(((size_t)b * 32 + (t >> 3)) * 256 + oo) * 8 + (t & 7)] = f2bf(acc[o]);
  }
  if (t < 16) {
    const int oo = oq * 16 + t;
    const float* mr = M + (size_t)b * CD * CD + oo * CD;
    float sv = bout[oo];
    for (int m = 0; m < CD; ++m) sv += mr[m] * bqkv[2 * CD + m];
    cvec[b * CD + oo] = sv;
  }
}

// out[b][o][n] = sum_c P[o][c] * bf16(x[b][c][n]) + cvec[b][o]
// Tile: 256 o x 128 n, K=256 fully LDS-resident -> barrier-free K-loop.
// xT LDS layout: row n (512 B) of 32 16-B slots, slot' = (c>>3) ^ (n&15).
__global__ __launch_bounds__(512) void out_k(const float* __restrict__ x,
                                             const unsigned short* __restrict__ Pf,
                                             const float* __restrict__ cvec,
                                             float* __restrict__ out) {
  __shared__ unsigned short xT[128 * 256];   // 64 KB
  const int t = threadIdx.x;
  const int nb = blockIdx.x, b = blockIdx.y;
  const int n0 = nb * 128;
  const int w = t >> 6, l = t & 63, l15 = l & 15, l4 = l >> 4;

  // ---- staging: coalesced row loads + thread-local 4x4 transpose ----
  {
    const int nbase = (w & 1) * 64 + l15 * 4;     // n-offset within tile
    const int cb0   = (w >> 1) * 16 + l4 * 4;     // c-base before it*64
#pragma unroll
    for (int it = 0; it < 4; ++it) {
      const int cb = cb0 + it * 64;
      const float* p = x + ((size_t)b * CD + cb) * ND + n0 + nbase;
      fx4 r0 = *(const fx4*)(p);
      fx4 r1 = *(const fx4*)(p + ND);
      fx4 r2 = *(const fx4*)(p + 2 * (size_t)ND);
      fx4 r3 = *(const fx4*)(p + 3 * (size_t)ND);
#pragma unroll
      for (int j = 0; j < 4; ++j) {
        const unsigned long long wlo =
            (unsigned long long)f2bf(r0[j]) |
            ((unsigned long long)f2bf(r1[j]) << 16) |
            ((unsigned long long)f2bf(r2[j]) << 32) |
            ((unsigned long long)f2bf(r3[j]) << 48);
        const int n = nbase + j;
        const int slot = ((cb >> 3) ^ (n & 15)) & 31;
        *(unsigned long long*)(&xT[n * 256 + slot * 8 + (cb & 7)]) = wlo;
      }
    }
  }
  __syncthreads();

  // ---- K loop: 8 steps of K=32, no barriers ----
  const int wr = w >> 1, wc = w & 1;   // 4 o-blocks x 2 n-blocks
  fx4 acc[4][4];
#pragma unroll
  for (int i = 0; i < 4; ++i)
#pragma unroll
    for (int j = 0; j < 4; ++j) acc[i][j] = (fx4){0.f, 0.f, 0.f, 0.f};

  const unsigned short* Pb = Pf + (size_t)b * 32 * 256 * 8;
  s8 afc[4], afn[4];
#pragma unroll
  for (int i = 0; i < 4; ++i) {
    const int o = wr * 64 + i * 16 + l15;
    afc[i] = *(const s8*)(Pb + ((size_t)(l4) * 256 + o) * 8);
  }
#pragma unroll
  for (int st = 0; st < 8; ++st) {
    if (st < 7) {
      const int kq = (st + 1) * 4 + l4;
#pragma unroll
      for (int i = 0; i < 4; ++i) {
        const int o = wr * 64 + i * 16 + l15;
        afn[i] = *(const s8*)(Pb + ((size_t)kq * 256 + o) * 8);
      }
    }
#pragma unroll
    for (int j = 0; j < 4; ++j) {
      const int n = wc * 64 + j * 16 + l15;
      const int slot = ((st * 4 + l4) ^ (n & 15)) & 31;
      s8 bf_ = *(const s8*)(&xT[n * 256 + slot * 8]);
#pragma unroll
      for (int i = 0; i < 4; ++i)
        acc[i][j] = __builtin_amdgcn_mfma_f32_16x16x32_bf16(afc[i], bf_, acc[i][j], 0, 0, 0);
    }
#pragma unroll
    for (int i = 0; i < 4; ++i) afc[i] = afn[i];
  }

  // ---- epilogue (nontemporal: 512 MB stream, keep x resident in L3) ----
  const float* cp = cvec + b * CD;
  float* ob = out + (size_t)b * CD * ND + n0;
#pragma unroll
  for (int i = 0; i < 4; ++i)
#pragma unroll
    for (int q = 0; q < 4; ++q) {
      const int o = wr * 64 + i * 16 + l4 * 4 + q;
      const float ad = cp[o];
#pragma unroll
      for (int j = 0; j < 4; ++j) {
        const int n = wc * 64 + j * 16 + l15;
        __builtin_nontemporal_store(acc[i][j][q] + ad, &ob[(size_t)o * ND + n]);
      }
    }
}

extern "C" void kernel_launch(void* const* d_in, const int* in_sizes, int n_in,
                              void* d_out, int out_size, void* d_ws, size_t ws_size,
                              hipStream_t stream) {
  const float* x    = (const float*)d_in[0];
  const float* Wqkv = (const float*)d_in[1];
  const float* bqkv = (const float*)d_in[2];
  const float* Wout = (const float*)d_in[3];
  const float* bout = (const float*)d_in[4];
  float* out = (float*)d_out;

  char* ws = (char*)d_ws;
  float*          Gsum = (float*)(ws + 0);                // 2 MB
  float*          r    = (float*)(ws + 2097152);          // 8 KB
  float*          Qt   = (float*)(ws + 2105344);          // 2 MB
  float*          Mm   = (float*)(ws + 4202496);          // 2 MB
  unsigned short* Pf   = (unsigned short*)(ws + 6299648); // 1 MB
  float*          cvec = (float*)(ws + 7348224);          // 8 KB
  float*          Gpart= (float*)(ws + 7356416);          // 32 MB
  const size_t NEED = 7356416ULL + (size_t)BD * GS * CD * CD * 4;  // ~40.9 MB

  const bool partial = (ws_size >= NEED);
  if (partial) {
    hipMemsetAsync(r, 0, 8192, stream);                   // r only
    gram_k<<<dim3(GS, 2, BD), 512, 0, stream>>>(x, Gpart, r, 0);
    reduce_k<<<dim3(512), 256, 0, stream>>>(Gpart, Gsum);
  } else {
    hipMemsetAsync(ws, 0, 2105344, stream);               // Gsum + r
    gram_k<<<dim3(GS, 2, BD), 512, 0, stream>>>(x, Gsum, r, 1);
  }
  qg_k   <<<dim3(4, NH, BD),  256, 0, stream>>>(Wqkv, Gsum, Qt);
  attn_k <<<dim3(NH, BD),     256, 0, stream>>>(Wqkv, bqkv, Wout, Qt, r, Mm);
  pproj_k<<<dim3(16, BD),     256, 0, stream>>>(Wqkv, bqkv, bout, Mm, Pf, cvec);
  out_k  <<<dim3(ND / 128, BD), 512, 0, stream>>>(x, Pf, cvec, out);
}

// Round 4
// 242.098 us; speedup vs baseline: 1.4583x; 1.0156x over previous
//
#include <hip/hip_runtime.h>

typedef __attribute__((ext_vector_type(4))) float  fx4;
typedef __attribute__((ext_vector_type(8))) short  s8;
typedef __attribute__((ext_vector_type(8))) unsigned short u8;
typedef __attribute__((ext_vector_type(4))) _Float16 hx4;

#define BD   8
#define CD   256
#define ND   16384
#define NH   8
#define DH   32
#define SCALE 0.17677669529663687f   // 1/sqrt(32)

#define GS     32           // split-K factor
#define GKB    (ND / GS)    // 512 fp32 cols per block
#define GNSTEP (GKB / 32)   // 16 K-steps of 32 cols

__device__ __forceinline__ unsigned short f2bf(float f) {
  unsigned int u = __float_as_uint(f);
  u += 0x7fffu + ((u >> 16) & 1u);      // RNE
  return (unsigned short)(u >> 16);
}
__device__ __forceinline__ float bf2f(unsigned short b) {
  return __uint_as_float(((unsigned int)b) << 16);
}

// convert 16 fp32 (one thread's 16 contiguous cols) into hi/lo bf16 and write
// to swizzled LDS slots. Row layout: 64 bf16 = 8 slots of 8 elems (16B);
// slot' = slot ^ (row&7). hi -> slots 0..3 (k=0..31), lo -> slots 4..7.
__device__ __forceinline__ void cvtw(unsigned short* rb, int half, int sw,
                                     fx4 d0, fx4 d1, fx4 d2, fx4 d3, float& rsum) {
  float f[16];
#pragma unroll
  for (int i = 0; i < 4; ++i) { f[i] = d0[i]; f[4+i] = d1[i]; f[8+i] = d2[i]; f[12+i] = d3[i]; }
  u8 hv[2], lv[2];
#pragma unroll
  for (int g = 0; g < 2; ++g) {
#pragma unroll
    for (int i = 0; i < 8; ++i) {
      float fv = f[g*8 + i];
      rsum += fv;
      unsigned short h = f2bf(fv);
      hv[g][i] = h;
      lv[g][i] = f2bf(fv - bf2f(h));
    }
  }
#pragma unroll
  for (int g = 0; g < 2; ++g) {
    *(u8*)(rb + (((half*2 + g)     ^ sw) * 8)) = hv[g];
    *(u8*)(rb + (((4 + half*2 + g) ^ sw) * 8)) = lv[g];
  }
}

// G = x x^T via bf16 hi/lo MFMA (HH^T + LH^T + HL^T).
// Block (s, b): full 256x256 tile, K-slab s (512 cols). 8 waves of 64x128.
// Partial mode: fp16 stores to Gpart[b][s]; atomic mode: atomicAdd into Gsum.
// Prefetch depth 2: loads for step st+2 issue at top of step st.
__global__ __launch_bounds__(512) void gram_k(const float* __restrict__ x,
                                              _Float16* __restrict__ Gp,
                                              float* __restrict__ Gsum,
                                              float* __restrict__ r,
                                              int atomic_mode) {
  __shared__ unsigned short sb[2][256 * 64];   // 64 KB double-buffered
  const int t = threadIdx.x;
  const int s = blockIdx.x, b = blockIdx.y;
  const int row = t >> 1, half = t & 1;
  const int sw = row & 7;
  const float* xp = x + ((size_t)b * CD + row) * ND + s * GKB + half * 16;
  const int wv = t >> 6, lane = t & 63, l15 = lane & 15, l4 = lane >> 4;
  const int wr = wv >> 1, wc = wv & 1;   // 4 row-groups x 2 col-groups (64x128/wave)

  float rsum = 0.f;
  fx4 a0 = *(const fx4*)(xp + 0);
  fx4 a1 = *(const fx4*)(xp + 4);
  fx4 a2 = *(const fx4*)(xp + 8);
  fx4 a3 = *(const fx4*)(xp + 12);
  fx4 b0 = *(const fx4*)(xp + 32);
  fx4 b1 = *(const fx4*)(xp + 36);
  fx4 b2 = *(const fx4*)(xp + 40);
  fx4 b3 = *(const fx4*)(xp + 44);

  fx4 acc[4][8];
#pragma unroll
  for (int i = 0; i < 4; ++i)
#pragma unroll
    for (int j = 0; j < 8; ++j)
      acc[i][j] = (fx4){0.f, 0.f, 0.f, 0.f};

  cvtw(&sb[0][row * 64], half, sw, a0, a1, a2, a3, rsum);
  __syncthreads();

#define GCOMPUTE(BP)                                                          \
  {                                                                           \
    const unsigned short* bp = (BP);                                          \
    s8 aH[4], aL[4];                                                          \
    _Pragma("unroll")                                                         \
    for (int i = 0; i < 4; ++i) {                                             \
      const int R = wr * 64 + i * 16 + l15;                                   \
      const int rs = R & 7;                                                   \
      const unsigned short* rp = bp + R * 64;                                 \
      aH[i] = *(const s8*)(rp + ((l4       ^ rs) * 8));                       \
      aL[i] = *(const s8*)(rp + (((4 + l4) ^ rs) * 8));                       \
    }                                                                         \
    _Pragma("unroll")                                                         \
    for (int j = 0; j < 8; ++j) {                                             \
      const int Rc = wc * 128 + j * 16 + l15;                                 \
      const int rs = Rc & 7;                                                  \
      const unsigned short* rp = bp + Rc * 64;                                \
      s8 bH = *(const s8*)(rp + ((l4 ^ rs) * 8));                             \
      _Pragma("unroll")                                                       \
      for (int i = 0; i < 4; ++i)                                             \
        acc[i][j] = __builtin_amdgcn_mfma_f32_16x16x32_bf16(aH[i], bH, acc[i][j], 0, 0, 0); \
      _Pragma("unroll")                                                       \
      for (int i = 0; i < 4; ++i)                                             \
        acc[i][j] = __builtin_amdgcn_mfma_f32_16x16x32_bf16(aL[i], bH, acc[i][j], 0, 0, 0); \
    }                                                                         \
    _Pragma("unroll")                                                         \
    for (int j = 0; j < 8; ++j) {                                             \
      const int Rc = wc * 128 + j * 16 + l15;                                 \
      const int rs = Rc & 7;                                                  \
      const unsigned short* rp = bp + Rc * 64;                                \
      s8 bL = *(const s8*)(rp + (((4 + l4) ^ rs) * 8));                       \
      _Pragma("unroll")                                                       \
      for (int i = 0; i < 4; ++i)                                             \
        acc[i][j] = __builtin_amdgcn_mfma_f32_16x16x32_bf16(aH[i], bL, acc[i][j], 0, 0, 0); \
    }                                                                         \
  }

#pragma unroll 1
  for (int it = 0; it < GNSTEP / 2; ++it) {
    const int st = it * 2;
    // even step: compute buf0(st); prefetch A <- st+2; cvtw B(st+1) -> buf1
    if (st + 2 < GNSTEP) {
      const float* p = xp + (st + 2) * 32;
      a0 = *(const fx4*)(p + 0);  a1 = *(const fx4*)(p + 4);
      a2 = *(const fx4*)(p + 8);  a3 = *(const fx4*)(p + 12);
    }
    GCOMPUTE(&sb[0][0]);
    cvtw(&sb[1][row * 64], half, sw, b0, b1, b2, b3, rsum);
    __syncthreads();
    // odd step: compute buf1(st+1); prefetch B <- st+3; cvtw A(st+2) -> buf0
    if (st + 3 < GNSTEP) {
      const float* p = xp + (st + 3) * 32;
      b0 = *(const fx4*)(p + 0);  b1 = *(const fx4*)(p + 4);
      b2 = *(const fx4*)(p + 8);  b3 = *(const fx4*)(p + 12);
    }
    GCOMPUTE(&sb[1][0]);
    if (st + 2 < GNSTEP)
      cvtw(&sb[0][row * 64], half, sw, a0, a1, a2, a3, rsum);
    __syncthreads();
  }
#undef GCOMPUTE

  float r2 = rsum + __shfl_down(rsum, 1);
  if ((t & 1) == 0) atomicAdd(&r[b * CD + row], r2);

  if (atomic_mode) {
    float* Gb = Gsum + (size_t)b * CD * CD;
#pragma unroll
    for (int i = 0; i < 4; ++i)
#pragma unroll
      for (int j = 0; j < 8; ++j)
#pragma unroll
        for (int q = 0; q < 4; ++q) {
          const int gr = wr * 64 + i * 16 + l4 * 4 + q;
          const int gc = wc * 128 + j * 16 + l15;
          atomicAdd(&Gb[gr * CD + gc], acc[i][j][q]);
        }
  } else {
    _Float16* Gb = Gp + ((size_t)(b * GS + s)) * CD * CD;
#pragma unroll
    for (int i = 0; i < 4; ++i)
#pragma unroll
      for (int j = 0; j < 8; ++j)
#pragma unroll
        for (int q = 0; q < 4; ++q) {
          const int gr = wr * 64 + i * 16 + l4 * 4 + q;
          const int gc = wc * 128 + j * 16 + l15;
          Gb[gr * CD + gc] = (_Float16)acc[i][j][q];
        }
  }
}

// Gsum[b] = sum_s Gpart[b][s]   (fp16 partials -> fp32)
__global__ __launch_bounds__(256) void reduce_k(const _Float16* __restrict__ Gpart,
                                                float* __restrict__ Gsum) {
  const int gid = blockIdx.x * 256 + threadIdx.x;   // 131072 fx4 total
  const int b = gid >> 14;                          // 16384 fx4 per batch
  const int e = gid & 16383;
  const _Float16* p = Gpart + (size_t)b * GS * 65536 + (size_t)e * 4;
  fx4 sv = (fx4){0.f, 0.f, 0.f, 0.f};
#pragma unroll
  for (int k = 0; k < GS; ++k) {
    hx4 hv = *(const hx4*)(p + (size_t)k * 65536);
#pragma unroll
    for (int q = 0; q < 4; ++q) sv[q] += (float)hv[q];
  }
  *(fx4*)(Gsum + (size_t)b * 65536 + (size_t)e * 4) = sv;
}

// Qt[b][h][dd][c] = sum_m Wq[h*32+dd][m] * G[b][m][c]   (fp32)
__global__ __launch_bounds__(256) void qg_k(const float* __restrict__ Wqkv,
                                            const float* __restrict__ G,
                                            float* __restrict__ Qt) {
  const int cq = blockIdx.x, h = blockIdx.y, b = blockIdx.z;
  const int t = threadIdx.x;
  const int c = cq * 64 + (t & 63);
  const int ms = t >> 6;
  const float* Gb = G + (size_t)b * CD * CD;
  const float* wqb = Wqkv + (size_t)(h * DH) * CD;
  float acc[32];
#pragma unroll
  for (int i = 0; i < 32; ++i) acc[i] = 0.f;
  for (int m = ms * 64; m < ms * 64 + 64; ++m) {
    const float gv = Gb[m * CD + c];
    const float* wq = wqb + m;
#pragma unroll
    for (int dd = 0; dd < 32; ++dd)
      acc[dd] += wq[dd * CD] * gv;
  }
  __shared__ float red[4][32][64];
#pragma unroll
  for (int dd = 0; dd < 32; ++dd) red[ms][dd][t & 63] = acc[dd];
  __syncthreads();
  for (int i = t; i < 32 * 64; i += 256) {
    const int dd = i >> 6, cc = i & 63;
    const float v = red[0][dd][cc] + red[1][dd][cc] + red[2][dd][cc] + red[3][dd][cc];
    Qt[(((size_t)b * NH + h) * DH + dd) * CD + cq * 64 + cc] = v;
  }
}

// S, softmax, and M[o][h*32+e] = sum_dd Wout[o][dd*8+h] * attn[dd][e]
__global__ __launch_bounds__(256) void attn_k(const float* __restrict__ Wqkv,
                                              const float* __restrict__ bqkv,
                                              const float* __restrict__ Wout,
                                              const float* __restrict__ Qt,
                                              const float* __restrict__ r,
                                              float* __restrict__ M) {
  const int h = blockIdx.x, b = blockIdx.y;
  const int t = threadIdx.x;
  __shared__ float S[32][33];
  __shared__ float A[32][33];
  __shared__ float wqr[32], wkr[32];
  __shared__ float wred[64][4];
  const float* rb = r + b * CD;
  {
    const int rowid = t & 63;            // (isk<<5)|dd
    const int q = t >> 6;                // quarter of the 256-c dot
    const int isk = rowid >> 5, dd = rowid & 31;
    const float* w = Wqkv + (size_t)(isk * CD + h * DH + dd) * CD + q * 64;
    const float* rq = rb + q * 64;
    float sv = 0.f;
#pragma unroll
    for (int cc = 0; cc < 64; ++cc) sv += w[cc] * rq[cc];
    wred[rowid][q] = sv;
  }
  __syncthreads();
  if (t < 64) {
    const float sv = wred[t][0] + wred[t][1] + wred[t][2] + wred[t][3];
    if (t >> 5) wkr[t & 31] = sv; else wqr[t & 31] = sv;
  }
  __syncthreads();
  {
    const int dd = t >> 3;
    const float* q = Qt + (((size_t)b * NH + h) * DH + dd) * CD;
    const float bq = bqkv[h * DH + dd];
#pragma unroll
    for (int u = 0; u < 4; ++u) {
      const int e = (t & 7) * 4 + u;
      const float bk = bqkv[CD + h * DH + e];
      const float* kw = Wqkv + (size_t)(CD + h * DH + e) * CD;
      float sv = 0.f;
      for (int cc = 0; cc < CD; ++cc) sv += q[cc] * kw[cc];
      sv += bq * wkr[e] + bk * wqr[dd] + (float)ND * bq * bk;
      S[dd][e] = sv * SCALE;
    }
  }
  __syncthreads();
  if (t < 32) {
    float mx = -1e30f;
#pragma unroll
    for (int e = 0; e < 32; ++e) mx = fmaxf(mx, S[t][e]);
    float sum = 0.f;
#pragma unroll
    for (int e = 0; e < 32; ++e) sum += __expf(S[t][e] - mx);
    const float inv = 1.f / sum;
#pragma unroll
    for (int e = 0; e < 32; ++e) A[t][e] = __expf(S[t][e] - mx) * inv;
  }
  __syncthreads();
  {
    float wrow[32];
#pragma unroll
    for (int dd = 0; dd < 32; ++dd) wrow[dd] = Wout[(size_t)t * CD + dd * NH + h];
    for (int e = 0; e < 32; ++e) {
      float sv = 0.f;
#pragma unroll
      for (int dd = 0; dd < 32; ++dd) sv += wrow[dd] * A[dd][e];
      M[((size_t)b * CD + t) * CD + h * DH + e] = sv;
    }
  }
}

// P = M @ Wv stored bf16 in MFMA-fragment order Pf[b][kq][o][8] (kq = c>>3),
// cvec = M @ bv + bout.
__global__ __launch_bounds__(256) void pproj_k(const float* __restrict__ Wqkv,
                                               const float* __restrict__ bqkv,
                                               const float* __restrict__ bout,
                                               const float* __restrict__ M,
                                               unsigned short* __restrict__ Pf,
                                               float* __restrict__ cvec) {
  const int oq = blockIdx.x, b = blockIdx.y;
  const int t = threadIdx.x;                 // t = c
  const float* Mb = M + (size_t)b * CD * CD + oq * 16 * CD;
  const float* Wv = Wqkv + (size_t)2 * CD * CD;
  float acc[16];
#pragma unroll
  for (int i = 0; i < 16; ++i) acc[i] = 0.f;
  for (int m = 0; m < CD; ++m) {
    const float wvv = Wv[(size_t)m * CD + t];
#pragma unroll
    for (int o = 0; o < 16; ++o) acc[o] += Mb[o * CD + m] * wvv;
  }
#pragma unroll
  for (int o = 0; o < 16; ++o) {
    const int oo = oq * 16 + o;
    Pf[(((size_t)b * 32 + (t >> 3)) * 256 + oo) * 8 + (t & 7)] = f2bf(acc[o]);
  }
  if (t < 16) {
    const int oo = oq * 16 + t;
    const float* mr = M + (size_t)b * CD * CD + oo * CD;
    float sv = bout[oo];
    for (int m = 0; m < CD; ++m) sv += mr[m] * bqkv[2 * CD + m];
    cvec[b * CD + oo] = sv;
  }
}

// out[b][o][n] = sum_c P[o][c] * bf16(x[b][c][n]) + cvec[b][o]
// Tile: 256 o x 128 n, K=256 fully LDS-resident -> barrier-free K-loop.
// xT LDS layout: row n (512 B) of 32 16-B slots, slot' = (c>>3) ^ (n&15).
__global__ __launch_bounds__(512) void out_k(const float* __restrict__ x,
                                             const unsigned short* __restrict__ Pf,
                                             const float* __restrict__ cvec,
                                             float* __restrict__ out) {
  __shared__ unsigned short xT[128 * 256];   // 64 KB
  const int t = threadIdx.x;
  const int nb = blockIdx.x, b = blockIdx.y;
  const int n0 = nb * 128;
  const int w = t >> 6, l = t & 63, l15 = l & 15, l4 = l >> 4;

  // ---- staging: coalesced row loads + thread-local 4x4 transpose ----
  {
    const int nbase = (w & 1) * 64 + l15 * 4;     // n-offset within tile
    const int cb0   = (w >> 1) * 16 + l4 * 4;     // c-base before it*64
#pragma unroll
    for (int it = 0; it < 4; ++it) {
      const int cb = cb0 + it * 64;
      const float* p = x + ((size_t)b * CD + cb) * ND + n0 + nbase;
      fx4 r0 = *(const fx4*)(p);
      fx4 r1 = *(const fx4*)(p + ND);
      fx4 r2 = *(const fx4*)(p + 2 * (size_t)ND);
      fx4 r3 = *(const fx4*)(p + 3 * (size_t)ND);
#pragma unroll
      for (int j = 0; j < 4; ++j) {
        const unsigned long long wlo =
            (unsigned long long)f2bf(r0[j]) |
            ((unsigned long long)f2bf(r1[j]) << 16) |
            ((unsigned long long)f2bf(r2[j]) << 32) |
            ((unsigned long long)f2bf(r3[j]) << 48);
        const int n = nbase + j;
        const int slot = ((cb >> 3) ^ (n & 15)) & 31;
        *(unsigned long long*)(&xT[n * 256 + slot * 8 + (cb & 7)]) = wlo;
      }
    }
  }
  __syncthreads();

  // ---- K loop: 8 steps of K=32, no barriers ----
  const int wr = w >> 1, wc = w & 1;   // 4 o-blocks x 2 n-blocks
  fx4 acc[4][4];
#pragma unroll
  for (int i = 0; i < 4; ++i)
#pragma unroll
    for (int j = 0; j < 4; ++j) acc[i][j] = (fx4){0.f, 0.f, 0.f, 0.f};

  const unsigned short* Pb = Pf + (size_t)b * 32 * 256 * 8;
  s8 afc[4], afn[4];
#pragma unroll
  for (int i = 0; i < 4; ++i) {
    const int o = wr * 64 + i * 16 + l15;
    afc[i] = *(const s8*)(Pb + ((size_t)(l4) * 256 + o) * 8);
  }
#pragma unroll
  for (int st = 0; st < 8; ++st) {
    if (st < 7) {
      const int kq = (st + 1) * 4 + l4;
#pragma unroll
      for (int i = 0; i < 4; ++i) {
        const int o = wr * 64 + i * 16 + l15;
        afn[i] = *(const s8*)(Pb + ((size_t)kq * 256 + o) * 8);
      }
    }
#pragma unroll
    for (int j = 0; j < 4; ++j) {
      const int n = wc * 64 + j * 16 + l15;
      const int slot = ((st * 4 + l4) ^ (n & 15)) & 31;
      s8 bf_ = *(const s8*)(&xT[n * 256 + slot * 8]);
#pragma unroll
      for (int i = 0; i < 4; ++i)
        acc[i][j] = __builtin_amdgcn_mfma_f32_16x16x32_bf16(afc[i], bf_, acc[i][j], 0, 0, 0);
    }
#pragma unroll
    for (int i = 0; i < 4; ++i) afc[i] = afn[i];
  }

  // ---- epilogue (nontemporal: out is a pure stream, keep x resident in L3) ----
  const float* cp = cvec + b * CD;
  float* ob = out + (size_t)b * CD * ND + n0;
#pragma unroll
  for (int i = 0; i < 4; ++i)
#pragma unroll
    for (int q = 0; q < 4; ++q) {
      const int o = wr * 64 + i * 16 + l4 * 4 + q;
      const float ad = cp[o];
#pragma unroll
      for (int j = 0; j < 4; ++j) {
        const int n = wc * 64 + j * 16 + l15;
        __builtin_nontemporal_store(acc[i][j][q] + ad, &ob[(size_t)o * ND + n]);
      }
    }
}

extern "C" void kernel_launch(void* const* d_in, const int* in_sizes, int n_in,
                              void* d_out, int out_size, void* d_ws, size_t ws_size,
                              hipStream_t stream) {
  const float* x    = (const float*)d_in[0];
  const float* Wqkv = (const float*)d_in[1];
  const float* bqkv = (const float*)d_in[2];
  const float* Wout = (const float*)d_in[3];
  const float* bout = (const float*)d_in[4];
  float* out = (float*)d_out;

  char* ws = (char*)d_ws;
  float*          Gsum = (float*)(ws + 0);                // 2 MB
  float*          r    = (float*)(ws + 2097152);          // 8 KB
  float*          Qt   = (float*)(ws + 2105344);          // 2 MB
  float*          Mm   = (float*)(ws + 4202496);          // 2 MB
  unsigned short* Pf   = (unsigned short*)(ws + 6299648); // 1 MB
  float*          cvec = (float*)(ws + 7348224);          // 8 KB
  _Float16*       Gpart= (_Float16*)(ws + 7356416);       // 32 MB (fp16, GS=32)
  const size_t NEED = 7356416ULL + (size_t)BD * GS * CD * CD * 2;  // ~40.9 MB

  const bool partial = (ws_size >= NEED);
  if (partial) {
    hipMemsetAsync(r, 0, 8192, stream);                   // r only
    gram_k<<<dim3(GS, BD), 512, 0, stream>>>(x, Gpart, Gsum, r, 0);
    reduce_k<<<dim3(512), 256, 0, stream>>>(Gpart, Gsum);
  } else {
    hipMemsetAsync(ws, 0, 2105344, stream);               // Gsum + r
    gram_k<<<dim3(GS, BD), 512, 0, stream>>>(x, Gpart, Gsum, r, 1);
  }
  qg_k   <<<dim3(4, NH, BD),  256, 0, stream>>>(Wqkv, Gsum, Qt);
  attn_k <<<dim3(NH, BD),     256, 0, stream>>>(Wqkv, bqkv, Wout, Qt, r, Mm);
  pproj_k<<<dim3(16, BD),     256, 0, stream>>>(Wqkv, bqkv, bout, Mm, Pf, cvec);
  out_k  <<<dim3(ND / 128, BD), 512, 0, stream>>>(x, Pf, cvec, out);
}